// Round 7
// baseline (509.602 us; speedup 1.0000x reference)
//
#include <hip/hip_runtime.h>

// out[B=16384, ONUM=512] = x[B, INUM=4096] @ wB[ONUM, INUM]^T, wB = (u < weight)
// v6: movement-bound fix. (1) pre-convert x -> bf16 (xb, 128MB in d_ws) so the
// GEMM has ZERO f2bf VALU and stages A via global_load_lds; (2) 64x64 wave tile
// (acc[4][4], 4 waves per 128x128 block) halves ds_read bytes/FLOP; (3) keep the
// proven zero-conflict content swizzle + single-barrier dbuf skeleton + XCD swz.
// Runtime ws_size guard: falls back to the proven v5 GEMM if d_ws < 132 MB.

#define M_DIM 16384
#define N_DIM 512
#define K_DIM 4096

using bf16x8 = __attribute__((ext_vector_type(8))) short;
using f32x4  = __attribute__((ext_vector_type(4))) float;

typedef __attribute__((address_space(1))) const void glb_cv;
typedef __attribute__((address_space(3))) void lds_v;

__device__ __forceinline__ unsigned short f2bf(float f) {
    union { float f; unsigned int u; } v;
    v.f = f;
    unsigned int r = v.u + 0x7FFFu + ((v.u >> 16) & 1u);   // RNE
    return (unsigned short)(r >> 16);
}

// ---------------- binarize: wB[o,k] = (u < weight) ? 1.0bf16 : 0 ----------------
__global__ __launch_bounds__(256) void binarize_kernel(const float* __restrict__ w,
                                                       const float* __restrict__ u,
                                                       unsigned short* __restrict__ wb) {
    int i = (blockIdx.x * 256 + threadIdx.x) * 4;
    float4 wv = *(const float4*)(w + i);
    float4 uv = *(const float4*)(u + i);
    ushort4 o;
    o.x = (uv.x < wv.x) ? 0x3F80u : 0u;
    o.y = (uv.y < wv.y) ? 0x3F80u : 0u;
    o.z = (uv.z < wv.z) ? 0x3F80u : 0u;
    o.w = (uv.w < wv.w) ? 0x3F80u : 0u;
    *(ushort4*)(wb + i) = o;
}

// ---------------- convx: x fp32 -> bf16 (RNE), 8 elem/thread ----------------
__global__ __launch_bounds__(256) void convx_kernel(const float* __restrict__ x,
                                                    unsigned short* __restrict__ xb) {
    size_t i = ((size_t)blockIdx.x * 256 + threadIdx.x) * 8;
    float4 a = *(const float4*)(x + i);
    float4 b = *(const float4*)(x + i + 4);
    union { unsigned short h[8]; uint4 v; } o;
    o.h[0] = f2bf(a.x); o.h[1] = f2bf(a.y); o.h[2] = f2bf(a.z); o.h[3] = f2bf(a.w);
    o.h[4] = f2bf(b.x); o.h[5] = f2bf(b.y); o.h[6] = f2bf(b.z); o.h[7] = f2bf(b.w);
    *(uint4*)(xb + i) = o.v;
}

// ---------------- v6 GEMM: 128x128, BK=64, 4 waves, 64x64/wave, A+B both gll ----------------
// Content swizzle (16B chunks, 128B rows): phys chunk = logical ^ (row&7);
// realized by pre-swizzling the global SOURCE of global_load_lds (rule 21) and
// XOR-ing the read address. Proven 0-conflict pattern (v5 counters).
__global__ __launch_bounds__(256, 2) void gemm_xb_kernel(const unsigned short* __restrict__ xb,
                                                         const unsigned short* __restrict__ wb,
                                                         float* __restrict__ out) {
    __shared__ __attribute__((aligned(16))) unsigned short Asx[2][128][64];   // 32 KB
    __shared__ __attribute__((aligned(16))) unsigned short Bsx[2][128][64];   // 32 KB

    const int t    = threadIdx.x;
    const int lane = t & 63;
    const int wave = t >> 6;                  // 0..3

    // XCD-chunked swizzle: 512 blocks, 64/XCD; the 4 bn-sharers of a bm adjacent.
    const int bid = blockIdx.x;
    const int swz = (bid & 7) * 64 + (bid >> 3);
    const int bn  = swz & 3;
    const int bm  = swz >> 2;

    const int wm  = (wave >> 1) * 64;         // wave tile 64x64
    const int wn  = (wave & 1) * 64;
    const int khi = lane >> 4;                // 0..3
    const int l15 = lane & 15;
    const int sw  = l15 & 7;                  // == row&7 for every fragment row

    f32x4 acc[4][4] = {};

    const unsigned short* xg = xb + (size_t)(bm * 128) * K_DIM;
    const unsigned short* wg = wb + (size_t)(bn * 128) * K_DIM;

    // Stage one 128x64 bf16 tile (16 KB = 1024 x 16B chunks, 4 gll/thread).
#define GLTILE(dst, src, k0)                                                     \
    _Pragma("unroll")                                                            \
    for (int c = 0; c < 4; ++c) {                                                \
        int e   = c * 256 + t;                                                   \
        int row = e >> 3;                                                        \
        int lc  = (e & 7) ^ (row & 7);                                           \
        const unsigned short* gsrc = (src) + (size_t)row * K_DIM + (k0) + lc * 8;\
        unsigned short* ldst = (unsigned short*)(dst) + (size_t)e * 8;           \
        __builtin_amdgcn_global_load_lds((glb_cv*)(const void*)gsrc,             \
                                         (lds_v*)(void*)ldst, 16, 0, 0);         \
    }

#define CMP(cur)                                                                 \
    _Pragma("unroll")                                                            \
    for (int kk = 0; kk < 2; ++kk) {                                             \
        int pc = (((kk << 2) | khi) ^ sw) << 4;                                  \
        bf16x8 af[4], bfr[4];                                                    \
        _Pragma("unroll") for (int i = 0; i < 4; ++i)                            \
            af[i] = *(const bf16x8*)((const char*)&Asx[cur][0][0] +              \
                                     (wm + i * 16 + l15) * 128 + pc);            \
        _Pragma("unroll") for (int j = 0; j < 4; ++j)                            \
            bfr[j] = *(const bf16x8*)((const char*)&Bsx[cur][0][0] +             \
                                      (wn + j * 16 + l15) * 128 + pc);           \
        _Pragma("unroll") for (int i = 0; i < 4; ++i)                            \
            _Pragma("unroll") for (int j = 0; j < 4; ++j)                        \
                acc[i][j] = __builtin_amdgcn_mfma_f32_16x16x32_bf16(af[i], bfr[j], \
                                                                    acc[i][j], 0, 0, 0); \
    }

    // ---- prologue ----
    GLTILE(&Asx[0][0][0], xg, 0);
    GLTILE(&Bsx[0][0][0], wg, 0);
    __syncthreads();

    // ---- main loop: issue t+1 early, compute t, drain at step end ----
    int cur = 0;
    for (int kt = 0; kt < (K_DIM / 64) - 1; ++kt) {
        const int kn = (kt + 1) * 64;
        GLTILE(&Asx[cur ^ 1][0][0], xg, kn);
        GLTILE(&Bsx[cur ^ 1][0][0], wg, kn);
        CMP(cur);
        __syncthreads();               // vmcnt(0)+lgkm+barrier; glls had whole compute phase
        cur ^= 1;
    }
    CMP(cur);

    // ---- epilogue: C/D col=lane&15, row=(lane>>4)*4+reg ----
    const int col0 = bn * 128 + wn + l15;
    const int row0 = bm * 128 + wm + khi * 4;
#pragma unroll
    for (int i = 0; i < 4; ++i)
#pragma unroll
        for (int j = 0; j < 4; ++j)
#pragma unroll
            for (int r = 0; r < 4; ++r)
                out[(size_t)(row0 + i * 16 + r) * N_DIM + (col0 + j * 16)] = acc[i][j][r];
}

// ---------------- v5 GEMM (proven fallback, used only if ws too small) ----------------
__global__ __launch_bounds__(256, 4) void gemm_bin_kernel(const float* __restrict__ x,
                                                          const unsigned short* __restrict__ wb,
                                                          float* __restrict__ out) {
    __shared__ __attribute__((aligned(16))) unsigned short As[64][64];
    __shared__ __attribute__((aligned(16))) unsigned short Bs[2][128][64];

    const int t    = threadIdx.x;
    const int lane = t & 63;
    const int wave = t >> 6;

    const int bid = blockIdx.x;
    const int swz = (bid & 7) * 128 + (bid >> 3);
    const int bn  = swz & 3;
    const int bm  = swz >> 2;

    const int wm  = (wave >> 1) * 32;
    const int wn  = (wave & 1) * 64;
    const int khi = lane >> 4;
    const int l15 = lane & 15;
    const int sw  = l15 & 7;

    f32x4 acc[2][4] = {};

    const float* xg = x + (size_t)(bm * 64) * K_DIM;
    const unsigned short* wbg = wb + (size_t)(bn * 128) * K_DIM;

    float4 sa[4];

#define LOADA5(k0)                                                               \
    _Pragma("unroll")                                                            \
    for (int j = 0; j < 4; ++j) {                                                \
        int ch = j * 256 + t;                                                    \
        sa[j] = *(const float4*)(xg + (size_t)(ch >> 4) * K_DIM + (k0) + (ch & 15) * 4); \
    }

#define STOREA5                                                                  \
    _Pragma("unroll")                                                            \
    for (int j = 0; j < 4; ++j) {                                                \
        int ch   = j * 256 + t;                                                  \
        int row  = ch >> 4;                                                      \
        int col8 = ch & 15;                                                      \
        ushort4 h;                                                               \
        h.x = f2bf(sa[j].x); h.y = f2bf(sa[j].y);                                \
        h.z = f2bf(sa[j].z); h.w = f2bf(sa[j].w);                                \
        *(ushort4*)((char*)&As[0][0] + row * 128 +                               \
                    ((((col8 >> 1) ^ (row & 7)) << 4) | ((col8 & 1) << 3))) = h; \
    }

#define GLLB5(b, k0)                                                             \
    _Pragma("unroll")                                                            \
    for (int c = 0; c < 4; ++c) {                                                \
        int e   = c * 256 + t;                                                   \
        int row = e >> 3;                                                        \
        int lc  = (e & 7) ^ (row & 7);                                           \
        const unsigned short* gsrc = wbg + (size_t)row * K_DIM + (k0) + lc * 8;  \
        unsigned short* ldst = (unsigned short*)&Bs[b][0][0] + (size_t)e * 8;    \
        __builtin_amdgcn_global_load_lds((glb_cv*)(const void*)gsrc,             \
                                         (lds_v*)(void*)ldst, 16, 0, 0);         \
    }

#define COMPUTE5(bsc)                                                            \
    _Pragma("unroll")                                                            \
    for (int kk = 0; kk < 2; ++kk) {                                             \
        bf16x8 af[2], bfr[4];                                                    \
        int pc = (((kk << 2) | khi) ^ sw) << 4;                                  \
        _Pragma("unroll") for (int i = 0; i < 2; ++i)                            \
            af[i] = *(const bf16x8*)((const char*)&As[0][0] +                    \
                                     (wm + i * 16 + l15) * 128 + pc);            \
        _Pragma("unroll") for (int j = 0; j < 4; ++j)                            \
            bfr[j] = *(const bf16x8*)((const char*)(bsc) +                       \
                                      (wn + j * 16 + l15) * 128 + pc);           \
        _Pragma("unroll") for (int i = 0; i < 2; ++i)                            \
            _Pragma("unroll") for (int j = 0; j < 4; ++j)                        \
                acc[i][j] = __builtin_amdgcn_mfma_f32_16x16x32_bf16(af[i], bfr[j], \
                                                                    acc[i][j], 0, 0, 0); \
    }

    LOADA5(0);
    GLLB5(0, 0);
    STOREA5;
    __syncthreads();

    int cur = 0;
    for (int kt = 0; kt < 63; ++kt) {
        const int kn = (kt + 1) * 64;
        LOADA5(kn);
        GLLB5(cur ^ 1, kn);
        COMPUTE5(&Bs[cur][0][0]);
        asm volatile("s_waitcnt lgkmcnt(0)" ::: "memory");
        __builtin_amdgcn_s_barrier();
        STOREA5;
        __syncthreads();
        cur ^= 1;
    }
    COMPUTE5(&Bs[cur][0][0]);

    const int col0 = bn * 128 + wn + l15;
    const int row0 = bm * 64 + wm + khi * 4;
#pragma unroll
    for (int i = 0; i < 2; ++i)
#pragma unroll
        for (int j = 0; j < 4; ++j)
#pragma unroll
            for (int r = 0; r < 4; ++r)
                out[(size_t)(row0 + i * 16 + r) * N_DIM + (col0 + j * 16)] = acc[i][j][r];
}

extern "C" void kernel_launch(void* const* d_in, const int* in_sizes, int n_in,
                              void* d_out, int out_size, void* d_ws, size_t ws_size,
                              hipStream_t stream) {
    const float* x = (const float*)d_in[0];
    const float* w = (const float*)d_in[1];
    const float* u = (const float*)d_in[2];
    float* out = (float*)d_out;
    unsigned short* wb = (unsigned short*)d_ws;   // 512*4096*2 = 4 MB

    binarize_kernel<<<dim3(N_DIM * K_DIM / 4 / 256), dim3(256), 0, stream>>>(w, u, wb);

    const size_t need = (size_t)N_DIM * K_DIM * 2 + (size_t)M_DIM * K_DIM * 2;  // 4 + 128 MB
    if (ws_size >= need) {
        unsigned short* xbuf = wb + (size_t)N_DIM * K_DIM;   // offset 4 MB
        convx_kernel<<<dim3(M_DIM * K_DIM / 8 / 256), dim3(256), 0, stream>>>(x, xbuf);
        gemm_xb_kernel<<<dim3(512), dim3(256), 0, stream>>>(xbuf, wb, out);
    } else {
        gemm_bin_kernel<<<dim3(1024), dim3(256), 0, stream>>>(x, wb, out);
    }
}